// Round 8
// baseline (297.087 us; speedup 1.0000x reference)
//
#include <hip/hip_runtime.h>

// ---------------------------------------------------------------------------
// GEMM body: out[r0..r0+31, 0..255] = bn_relu?(in rows) @ W(128x256) + bias.
// 256 threads: thread = 4 cols (cg=t&63) x 8 rows (rg=t>>6).
// st: raw per-channel sums (st[c]) and sumsq (st[128+c]) over 2048 rows.
// ---------------------------------------------------------------------------
__device__ __forceinline__ void gemm_body(
    const float* __restrict__ in, const float* __restrict__ st,
    const float* __restrict__ gm, const float* __restrict__ bt,
    const float* __restrict__ W, const float* __restrict__ bi,
    float* __restrict__ out, int rb, void* smemv)
{
    float* rows  = (float*)smemv;           // 32*128 floats = 16384 B
    float* scale = rows + 4096;             // 128
    float* shift = scale + 128;             // 128
    int t = threadIdx.x;
    if (t < 128) {
        float sc = 1.0f, sf = 0.0f;
        if (st) {
            float mu  = st[t] * (1.0f/2048.0f);
            float var = st[128+t] * (1.0f/2048.0f) - mu*mu;
            sc = rsqrtf(var + 1e-5f) * gm[t];
            sf = bt[t] - mu*sc;
        }
        scale[t] = sc; shift[t] = sf;
    }
    __syncthreads();
    int r0 = rb * 32;
    const float4* in4 = (const float4*)(in + r0*128);
    float4* rows4 = (float4*)rows;
    bool bn = (st != 0);
    for (int q = t; q < 1024; q += 256) {
        float4 v = in4[q];
        if (bn) {
            int c4 = (q & 31) << 2;
            v.x = fmaxf(v.x*scale[c4  ] + shift[c4  ], 0.0f);
            v.y = fmaxf(v.y*scale[c4+1] + shift[c4+1], 0.0f);
            v.z = fmaxf(v.z*scale[c4+2] + shift[c4+2], 0.0f);
            v.w = fmaxf(v.w*scale[c4+3] + shift[c4+3], 0.0f);
        }
        rows4[q] = v;
    }
    __syncthreads();
    int cg = t & 63, rg = t >> 6;
    int rbase = rg * 8;
    float acc[8][4];
    #pragma unroll
    for (int r = 0; r < 8; ++r) { acc[r][0]=0.f; acc[r][1]=0.f; acc[r][2]=0.f; acc[r][3]=0.f; }
    const float4* W4 = (const float4*)W;
    for (int k = 0; k < 128; k += 4) {
        float4 a[8];
        #pragma unroll
        for (int r = 0; r < 8; ++r) a[r] = *(const float4*)&rows[(rbase+r)*128 + k];
        #pragma unroll
        for (int u = 0; u < 4; ++u) {
            float4 w = W4[(k+u)*64 + cg];
            #pragma unroll
            for (int r = 0; r < 8; ++r) {
                float av = (u==0) ? a[r].x : (u==1) ? a[r].y : (u==2) ? a[r].z : a[r].w;
                acc[r][0] += av*w.x; acc[r][1] += av*w.y;
                acc[r][2] += av*w.z; acc[r][3] += av*w.w;
            }
        }
    }
    float4 b4 = ((const float4*)bi)[cg];
    #pragma unroll
    for (int r = 0; r < 8; ++r) {
        float4 o;
        o.x = acc[r][0]+b4.x; o.y = acc[r][1]+b4.y;
        o.z = acc[r][2]+b4.z; o.w = acc[r][3]+b4.w;
        ((float4*)out)[(r0+rbase+r)*64 + cg] = o;
    }
}

// ---------------------------------------------------------------------------
// K1: wave-synchronous knn (blocks 0..511, 4 vertices/block = 1 per wave) +
// gemmA (512..703) + zero st (704..709) + dirs normalize (710).
// knn per wave: 16 dists/lane in regs -> wave-private 256-bin histogram ->
// rank-101 via shfl_up wave scan (2 radix rounds) -> compact <=P16 superset ->
// bitonic-256 fully in registers (4 keys/lane, shfl_xor cross-lane).
// Key = (sortable_dist<<32)|idx reproduces jax top_k order incl. ties.
// ---------------------------------------------------------------------------
__global__ void k1_kernel(const float* __restrict__ verts, const float* __restrict__ dirs,
                          const float* __restrict__ x,
                          const float* __restrict__ convW, const float* __restrict__ convB,
                          int* __restrict__ idxout, float* __restrict__ sdn,
                          float* __restrict__ st, float* __restrict__ fo)
{
    __shared__ __align__(16) char smem[28800];
    int t = threadIdx.x;
    int blk = blockIdx.x;

    if (blk >= 704) {
        if (blk == 710) {                          // dirs normalize: 6x128 columns
            for (int i = t; i < 768; i += 256) {
                int l = i >> 7, k = i & 127;
                float a = dirs[l*384 + k];
                float b = dirs[l*384 + 128 + k];
                float c = dirs[l*384 + 256 + k];
                float nrm = sqrtf(a*a + b*b + c*c);
                float inv = 1.0f / fmaxf(nrm, 1e-12f);
                sdn[l*384 + k]       = a*inv;
                sdn[l*384 + 128 + k] = b*inv;
                sdn[l*384 + 256 + k] = c*inv;
            }
        } else {                                   // zero st: 6 x 256 floats
            st[(blk - 704)*256 + t] = 0.0f;
        }
        return;
    }
    if (blk >= 512) {                              // gemmA: L0,L1,L3 from x (no BN)
        int g = blk - 512;
        int s = g >> 6, rb = g & 63;
        int wi = (s==0) ? 0 : (s==1) ? 1 : 3;
        gemm_body(x, (const float*)0, (const float*)0, (const float*)0,
                  convW + wi*32768, convB + wi*256, fo + s*524288, rb, smem);
        return;
    }

    // ---------------- knn: one wave per vertex ----------------
    float* xs  = (float*)smem;                     // 1024
    float* ys  = xs + 1024;
    float* zs  = ys + 1024;
    float* sqs = zs + 1024;                        // ends 16384 B
    unsigned long long* keysBase = (unsigned long long*)(smem + 16384); // 4x256 u64
    unsigned int* histBase = (unsigned int*)(smem + 24576);             // 4x256 u32
    unsigned int* selBase  = (unsigned int*)(smem + 28672);             // 4x4 u32

    int w = t >> 6;            // wave id 0..3
    int l = t & 63;            // lane
    int vglob = blk*4 + w;     // (b,v) handled by this wave
    int b = vglob >> 10;
    int v = vglob & 1023;
    unsigned long long* keys = keysBase + w*256;
    unsigned int* hist = histBase + w*256;
    unsigned int* sel  = selBase + w*4;

    const float* vb = verts + b * 3072;
    for (int i = t; i < 1024; i += 256) {
        float xx = vb[i*3+0], yy = vb[i*3+1], zz = vb[i*3+2];
        xs[i] = xx; ys[i] = yy; zs[i] = zz;
        sqs[i] = xx*xx + yy*yy + zz*zz;
    }
    __syncthreads();                               // B1

    float cx = xs[v], cy = ys[v], cz = zs[v], csq = sqs[v];
    unsigned long long K16[16];
    #pragma unroll
    for (int q = 0; q < 16; ++q) {
        int j = q*64 + l;
        float dot = cx*xs[j] + cy*ys[j] + cz*zs[j];
        float d = -2.0f*dot + csq + sqs[j];        // reference formula
        unsigned int u = __float_as_uint(d);
        u = (u & 0x80000000u) ? ~u : (u | 0x80000000u);
        K16[q] = (((unsigned long long)u) << 32) | (unsigned long long)j;
    }
    #pragma unroll
    for (int i = 0; i < 4; ++i) hist[l*4 + i] = 0u;
    __syncthreads();                               // B2

    #pragma unroll
    for (int q = 0; q < 16; ++q)
        atomicAdd(&hist[(unsigned int)(K16[q] >> 56)], 1u);
    __syncthreads();                               // B3

    // ---- wave scan round 1: find bin & remaining rank of rank-101
    {
        unsigned int h0 = hist[l*4], h1 = hist[l*4+1], h2 = hist[l*4+2], h3 = hist[l*4+3];
        unsigned int c1 = h0, c2 = h0+h1, c3 = h0+h1+h2, T = c3+h3;
        unsigned int xacc = T;
        #pragma unroll
        for (int off = 1; off < 64; off <<= 1) {
            unsigned int y = __shfl_up(xacc, off, 64);
            if (l >= off) xacc += y;
        }
        unsigned int P = xacc - T;                 // exclusive prefix
        unsigned int ex[4] = {P, P+c1, P+c2, P+c3};
        unsigned int hh[4] = {h0, h1, h2, h3};
        #pragma unroll
        for (int i = 0; i < 4; ++i) {
            if (ex[i] < 101u && ex[i] + hh[i] >= 101u) {
                sel[0] = (unsigned int)(l*4 + i);
                sel[1] = 101u - ex[i];
            }
        }
    }
    __syncthreads();                               // B4
    unsigned int P8 = sel[0], rank2 = sel[1];
    #pragma unroll
    for (int i = 0; i < 4; ++i) hist[l*4 + i] = 0u;
    __syncthreads();                               // B5

    #pragma unroll
    for (int q = 0; q < 16; ++q)
        if ((unsigned int)(K16[q] >> 56) == P8)
            atomicAdd(&hist[(unsigned int)(K16[q] >> 48) & 0xFFu], 1u);
    __syncthreads();                               // B6

    // ---- wave scan round 2: 16-bit prefix of rank-101 key
    {
        unsigned int h0 = hist[l*4], h1 = hist[l*4+1], h2 = hist[l*4+2], h3 = hist[l*4+3];
        unsigned int c1 = h0, c2 = h0+h1, c3 = h0+h1+h2, T = c3+h3;
        unsigned int xacc = T;
        #pragma unroll
        for (int off = 1; off < 64; off <<= 1) {
            unsigned int y = __shfl_up(xacc, off, 64);
            if (l >= off) xacc += y;
        }
        unsigned int P = xacc - T;
        unsigned int ex[4] = {P, P+c1, P+c2, P+c3};
        unsigned int hh[4] = {h0, h1, h2, h3};
        #pragma unroll
        for (int i = 0; i < 4; ++i) {
            if (ex[i] < rank2 && ex[i] + hh[i] >= rank2) {
                sel[2] = (P8 << 8) | (unsigned int)(l*4 + i);
                sel[3] = 0u;
            }
        }
    }
    __syncthreads();                               // B7
    unsigned int P16 = sel[2];

    // ---- compact superset (>=101 keys, <=256 kept) into wave-private LDS
    #pragma unroll
    for (int q = 0; q < 16; ++q) {
        if ((unsigned int)(K16[q] >> 48) <= P16) {
            unsigned int pos = atomicAdd(&sel[3], 1u);
            if (pos < 256u) keys[pos] = K16[q];
        }
    }
    __syncthreads();                               // B8
    unsigned int cnt = sel[3];

    // ---- load 4 keys/lane (e = l*4+q), pad, bitonic-256 in registers
    unsigned long long K[4];
    #pragma unroll
    for (int q = 0; q < 4; ++q) {
        unsigned int e = (unsigned int)(l*4 + q);
        K[q] = (e < cnt) ? keys[e] : 0xFFFFFFFFFFFFFFFFULL;
    }

    auto cswap = [&](int qa, int qb, int k) {
        int e = (l << 2) + qa;
        bool up = ((e & k) == 0);
        unsigned long long a = K[qa], bb2 = K[qb];
        unsigned long long mn = a < bb2 ? a : bb2;
        unsigned long long mx = a < bb2 ? bb2 : a;
        K[qa] = up ? mn : mx;
        K[qb] = up ? mx : mn;
    };
    #pragma unroll
    for (int k = 2; k <= 256; k <<= 1) {
        for (int j = k >> 1; j >= 4; j >>= 1) {
            int lj = j >> 2;
            #pragma unroll
            for (int q = 0; q < 4; ++q) {
                unsigned long long other = __shfl_xor(K[q], lj, 64);
                int e = (l << 2) + q;
                bool up = ((e & k) == 0);
                bool lower = ((l & lj) == 0);
                bool takeMin = (lower == up);
                unsigned long long mn = K[q] < other ? K[q] : other;
                unsigned long long mx = K[q] < other ? other : K[q];
                K[q] = takeMin ? mn : mx;
            }
        }
        if (k >= 4) { cswap(0, 2, k); cswap(1, 3, k); }
        cswap(0, 1, k); cswap(2, 3, k);
    }

    // ranks 1..100 (rank 0 = self)
    #pragma unroll
    for (int q = 0; q < 4; ++q) {
        int e = l*4 + q;
        if (e >= 1 && e <= 100)
            idxout[vglob*100 + (e-1)] = (int)(K[q] & 0xFFFFFFFFu);
    }
}

// ---------------------------------------------------------------------------
// Agg: prebn[r,k] = fo[r,k] + max_n relu(d_n.sd_k)*fo[nbr,128+k].
// blockIdx.x = row, blockIdx.y = slot. 128 threads = channels. Unroll 5.
// ---------------------------------------------------------------------------
__global__ void agg_kernel(const int* __restrict__ idx, const float* __restrict__ verts,
                           const float* __restrict__ sdn, const float* __restrict__ fo,
                           int n0, int n1, int n2, int d0, int d1, int d2,
                           float* o0, float* o1, float* o2)
{
    __shared__ float4 ds4[100];
    __shared__ int js[100];
    int slot = blockIdx.y;
    int n  = slot==0 ? n0 : slot==1 ? n1 : n2;
    int dI = slot==0 ? d0 : slot==1 ? d1 : d2;
    float* outp = slot==0 ? o0 : slot==1 ? o1 : o2;
    const float* fos = fo + slot * 524288;
    const float* sd = sdn + dI * 384;

    int r = blockIdx.x;
    int b = r >> 10;
    int t = threadIdx.x;
    if (t < n) {
        int j = idx[r*100 + t];
        js[t] = j;
        const float* pj = verts + (b*1024 + j)*3;
        const float* pv = verts + r*3;
        float dx = pj[0]-pv[0], dy = pj[1]-pv[1], dz = pj[2]-pv[2];
        float nm = sqrtf(dx*dx + dy*dy + dz*dz);
        float inv = 1.0f / fmaxf(nm, 1e-12f);
        ds4[t] = make_float4(dx*inv, dy*inv, dz*inv, 0.0f);
    }
    __syncthreads();
    float s0 = sd[t], s1 = sd[128+t], s2 = sd[256+t];
    int bb = b * 1024;
    float m = -3.0e38f;
    for (int q = 0; q < n; q += 5) {
        float th[5];
        const float* p[5];
        #pragma unroll
        for (int u = 0; u < 5; ++u) {
            float4 dq = ds4[q+u];
            th[u] = fmaxf(dq.x*s0 + dq.y*s1 + dq.z*s2, 0.0f);
            p[u] = fos + (size_t)(bb + js[q+u])*256 + 128 + t;
        }
        float vv[5];
        #pragma unroll
        for (int u = 0; u < 5; ++u) vv[u] = *p[u];
        #pragma unroll
        for (int u = 0; u < 5; ++u) m = fmaxf(m, th[u]*vv[u]);
    }
    outp[r*128 + t] = fos[r*256 + t] + m;
}

// ---------------------------------------------------------------------------
// BN stats: per-channel sum/sumsq over 2048 rows. grid (16, nslots).
// ---------------------------------------------------------------------------
__global__ void stats_kernel(const float* p0, const float* p1, const float* p2,
                             int i0, int i1, int i2, float* stats)
{
    int slot = blockIdx.y;
    const float* p = slot==0 ? p0 : slot==1 ? p1 : p2;
    float* st = stats + (slot==0 ? i0 : slot==1 ? i1 : i2) * 256;
    __shared__ float s1[256], s2[256];
    int t = threadIdx.x, k = t & 127, half = t >> 7;
    int r0 = blockIdx.x * 128;
    float sum = 0.0f, sq = 0.0f;
    for (int s = 0; s < 64; ++s) {
        float x = p[(r0 + half + 2*s)*128 + k];
        sum += x; sq += x*x;
    }
    s1[t] = sum; s2[t] = sq;
    __syncthreads();
    if (t < 128) {
        atomicAdd(&st[k],     s1[t] + s1[t+128]);
        atomicAdd(&st[128+k], s2[t] + s2[t+128]);
    }
}

// ---------------------------------------------------------------------------
// Standalone gemm, up to 2 slots via blockIdx.y. grid (64, nslots), 256 thr.
// ---------------------------------------------------------------------------
__global__ void gemm2_kernel(
    const float* inA, const float* stA, const float* gA, const float* beA,
    const float* WA, const float* biA, float* foA,
    const float* inB, const float* stB, const float* gB, const float* beB,
    const float* WB, const float* biB, float* foB)
{
    __shared__ __align__(16) char smem[17408];
    if (blockIdx.y == 0)
        gemm_body(inA, stA, gA, beA, WA, biA, foA, blockIdx.x, smem);
    else
        gemm_body(inB, stB, gB, beB, WB, biB, foB, blockIdx.x, smem);
}

// ---------------------------------------------------------------------------
// Down-proj: row = [bn(p0)|bn(p1)|bn(p2)] (384) -> relu(row @ dW + db).
// 16 rows/block (128 blocks). Thread = 2 cols x 8 rows.
// ---------------------------------------------------------------------------
__global__ void down_kernel(
    const float* __restrict__ p0, const float* __restrict__ st0,
    const float* __restrict__ g0, const float* __restrict__ be0,
    const float* __restrict__ p1, const float* __restrict__ st1,
    const float* __restrict__ g1, const float* __restrict__ be1,
    const float* __restrict__ p2, const float* __restrict__ st2,
    const float* __restrict__ g2, const float* __restrict__ be2,
    const float* __restrict__ dW, const float* __restrict__ db,
    float* __restrict__ out)
{
    __shared__ float rows[16*384];
    __shared__ float scale[384], shift[384];
    int t = threadIdx.x;
    int r0 = blockIdx.x * 16;
    for (int c = t; c < 384; c += 256) {
        int seg = c >> 7, cc = c & 127;
        const float* stp = seg==0 ? st0 : seg==1 ? st1 : st2;
        const float* g   = seg==0 ? g0  : seg==1 ? g1  : g2;
        const float* be  = seg==0 ? be0 : seg==1 ? be1 : be2;
        float mu  = stp[cc] * (1.0f/2048.0f);
        float var = stp[128+cc] * (1.0f/2048.0f) - mu*mu;
        float s = rsqrtf(var + 1e-5f) * g[cc];
        scale[c] = s;
        shift[c] = be[cc] - mu*s;
    }
    __syncthreads();
    #pragma unroll
    for (int seg = 0; seg < 3; ++seg) {
        const float* ps = seg==0 ? p0 : seg==1 ? p1 : p2;
        const float4* ps4 = (const float4*)(ps + r0*128);
        for (int q = t; q < 512; q += 256) {
            int row = q >> 5, c4 = (q & 31) << 2;
            float4 v = ps4[q];
            int sc = seg*128 + c4;
            v.x = fmaxf(v.x*scale[sc  ] + shift[sc  ], 0.0f);
            v.y = fmaxf(v.y*scale[sc+1] + shift[sc+1], 0.0f);
            v.z = fmaxf(v.z*scale[sc+2] + shift[sc+2], 0.0f);
            v.w = fmaxf(v.w*scale[sc+3] + shift[sc+3], 0.0f);
            *(float4*)&rows[row*384 + sc] = v;
        }
    }
    __syncthreads();
    int cg = t & 127, rg = t >> 7;
    int rbase = rg * 8;
    float acc[8][2];
    #pragma unroll
    for (int r = 0; r < 8; ++r) { acc[r][0] = 0.f; acc[r][1] = 0.f; }
    const float2* W2 = (const float2*)dW;
    for (int k = 0; k < 384; k += 4) {
        float4 a[8];
        #pragma unroll
        for (int r = 0; r < 8; ++r) a[r] = *(const float4*)&rows[(rbase+r)*384 + k];
        #pragma unroll
        for (int u = 0; u < 4; ++u) {
            float2 w = W2[(k+u)*128 + cg];
            #pragma unroll
            for (int r = 0; r < 8; ++r) {
                float av = (u==0) ? a[r].x : (u==1) ? a[r].y : (u==2) ? a[r].z : a[r].w;
                acc[r][0] += av*w.x; acc[r][1] += av*w.y;
            }
        }
    }
    float2 b2 = ((const float2*)db)[cg];
    #pragma unroll
    for (int r = 0; r < 8; ++r) {
        float2 o;
        o.x = fmaxf(acc[r][0] + b2.x, 0.0f);
        o.y = fmaxf(acc[r][1] + b2.y, 0.0f);
        ((float2*)out)[(r0+rbase+r)*128 + cg] = o;
    }
}

// ---------------------------------------------------------------------------
extern "C" void kernel_launch(void* const* d_in, const int* in_sizes, int n_in,
                              void* d_out, int out_size, void* d_ws, size_t ws_size,
                              hipStream_t stream)
{
    (void)in_sizes; (void)n_in; (void)out_size; (void)ws_size;
    const float* verts = (const float*)d_in[0];
    const float* x     = (const float*)d_in[1];
    const float* convW = (const float*)d_in[2];
    const float* convB = (const float*)d_in[3];
    const float* dirs  = (const float*)d_in[4];
    const float* gam   = (const float*)d_in[5];
    const float* bet   = (const float*)d_in[6];
    const float* dW    = (const float*)d_in[7];
    const float* db    = (const float*)d_in[8];
    float* out = (float*)d_out;

    char* ws = (char*)d_ws;
    int*   idxb = (int*)(ws);                    //  819200 B : (2048,100)
    float* sdn  = (float*)(ws + 819200);         //    9216 B : (6,3,128)
    float* st   = (float*)(ws + 828416);         //    6144 B : 6 x 256
    float* fo   = (float*)(ws + 834560);         // 6291456 B : 3 x (2048,256)
    float* p0   = (float*)(ws + 7126016);        // 1 MiB each: (2048,128)
    float* p1   = (float*)(ws + 8174592);
    float* p2   = (float*)(ws + 9223168);
    float* p3   = (float*)(ws + 10271744);
    float* p4   = (float*)(ws + 11320320);
    float* p5   = (float*)(ws + 12368896);       // total ~12.8 MiB

    const float* nf = (const float*)0;
    float* nw = (float*)0;
    float* st0 = st,        *st1 = st + 256,  *st2 = st + 512;
    float* st3 = st + 768,  *st4 = st + 1024, *st5 = st + 1280;

    // K1: wave-sync knn + gemmA (L0,L1,L3 from x) + zero st + dirs norm
    k1_kernel<<<711, 256, 0, stream>>>(verts, dirs, x, convW, convB,
                                       idxb, sdn, st, fo);
    // K2: aggA -> p0 (n5,d0), p1 (n20,d1), p3 (n100,d3)
    agg_kernel<<<dim3(2048,3), 128, 0, stream>>>(
        idxb, verts, sdn, fo, 5, 20, 100, 0, 1, 3, p0, p1, p3);
    // K3: statsA
    stats_kernel<<<dim3(16,3), 256, 0, stream>>>(p0, p1, p3, 0, 1, 3, st);
    // K4: gemmB: L2 from bn(p1,st1,g1,b1); L4 from bn(p3,st3,g3,b3)
    gemm2_kernel<<<dim3(64,2), 256, 0, stream>>>(
        p1, st1, gam + 128, bet + 128, convW + 65536,  convB + 512,  fo,
        p3, st3, gam + 384, bet + 384, convW + 131072, convB + 1024, fo + 524288);
    // K5: aggB -> p2 (n20,d2), p4 (n100,d4)
    agg_kernel<<<dim3(2048,2), 128, 0, stream>>>(
        idxb, verts, sdn, fo, 20, 100, 0, 2, 4, 0, p2, p4, nw);
    // K6: statsB
    stats_kernel<<<dim3(16,2), 256, 0, stream>>>(p2, p4, nf, 2, 4, 0, st);
    // K7: gemmC: L5-conv (params3) from bn(p4,st4,g4,b4)
    gemm2_kernel<<<dim3(64,1), 256, 0, stream>>>(
        p4, st4, gam + 512, bet + 512, convW + 98304, convB + 768, fo,
        nf, nf, nf, nf, nf, nf, nw);
    // K8: aggC -> p5 (n100,d3)
    agg_kernel<<<dim3(2048,1), 128, 0, stream>>>(
        idxb, verts, sdn, fo, 100, 0, 0, 3, 0, 0, p5, nw, nw);
    // K9: statsC
    stats_kernel<<<dim3(16,1), 256, 0, stream>>>(p5, nf, nf, 5, 0, 0, st);
    // K10: down: bn(p0,st0,g0,b0) | bn(p2,st2,g2,b2) | bn(p5,st5,g3,b3)
    down_kernel<<<128, 256, 0, stream>>>(
        p0, st0, gam, bet,
        p2, st2, gam + 256, bet + 256,
        p5, st5, gam + 384, bet + 384,
        dW, db, out);
}

// Round 9
// 214.943 us; speedup vs baseline: 1.3822x; 1.3822x over previous
//
#include <hip/hip_runtime.h>

// ---------------------------------------------------------------------------
// GEMM body: out[r0..r0+3, 0..255] = bn_relu?(in rows) @ W(128x256) + bias.
// 4 rows/block so grids stay >=512 on 256 CUs (>=2 waves/SIMD for latency
// hiding -- 32-row blocks measured 85us @ VALUBusy 0.03%, grid-starved).
// Thread = 1 row (t>>6) x 4 cols (t&63). st: raw per-channel sum/sumsq.
// ---------------------------------------------------------------------------
__device__ __forceinline__ void gemm_body(
    const float* __restrict__ in, const float* __restrict__ st,
    const float* __restrict__ gm, const float* __restrict__ bt,
    const float* __restrict__ W, const float* __restrict__ bi,
    float* __restrict__ out, int rb, void* smemv)
{
    float* rows  = (float*)smemv;           // 4*128 floats
    float* scale = rows + 512;              // 128
    float* shift = scale + 128;             // 128
    int t = threadIdx.x;
    if (t < 128) {
        float sc = 1.0f, sf = 0.0f;
        if (st) {
            float mu  = st[t] * (1.0f/2048.0f);
            float var = st[128+t] * (1.0f/2048.0f) - mu*mu;
            sc = rsqrtf(var + 1e-5f) * gm[t];
            sf = bt[t] - mu*sc;
        }
        scale[t] = sc; shift[t] = sf;
    }
    __syncthreads();
    int r0 = rb * 4;
    if (t < 128) {                          // stage 4 rows (128 float4s)
        float4 v = ((const float4*)(in + r0*128))[t];
        if (st) {
            int c4 = (t & 31) << 2;
            v.x = fmaxf(v.x*scale[c4  ] + shift[c4  ], 0.0f);
            v.y = fmaxf(v.y*scale[c4+1] + shift[c4+1], 0.0f);
            v.z = fmaxf(v.z*scale[c4+2] + shift[c4+2], 0.0f);
            v.w = fmaxf(v.w*scale[c4+3] + shift[c4+3], 0.0f);
        }
        ((float4*)rows)[t] = v;
    }
    __syncthreads();
    int cb = t & 63, row = t >> 6;
    const float* ar = rows + row*128;
    const float4* W4 = (const float4*)W;
    float4 acc = make_float4(0.f, 0.f, 0.f, 0.f);
    #pragma unroll 4
    for (int k = 0; k < 128; k += 4) {
        float4 a = *(const float4*)(ar + k);
        float4 w;
        w = W4[(k+0)*64+cb]; acc.x += a.x*w.x; acc.y += a.x*w.y; acc.z += a.x*w.z; acc.w += a.x*w.w;
        w = W4[(k+1)*64+cb]; acc.x += a.y*w.x; acc.y += a.y*w.y; acc.z += a.y*w.z; acc.w += a.y*w.w;
        w = W4[(k+2)*64+cb]; acc.x += a.z*w.x; acc.y += a.z*w.y; acc.z += a.z*w.z; acc.w += a.z*w.w;
        w = W4[(k+3)*64+cb]; acc.x += a.w*w.x; acc.y += a.w*w.y; acc.z += a.w*w.z; acc.w += a.w*w.w;
    }
    float4 b4 = ((const float4*)bi)[cb];
    acc.x += b4.x; acc.y += b4.y; acc.z += b4.z; acc.w += b4.w;
    ((float4*)out)[(r0+row)*64 + cb] = acc;
}

// ---------------------------------------------------------------------------
// K1: wave-sync knn (blocks 0..511, 1 vertex/wave) + gemmA (512..2047:
// 3 slots x 512 blocks of 4 rows) + zero st (2048..2053) + dirs norm (2054).
// knn: 16 dists/lane in regs -> wave-private 256-bin hist -> rank-101 via
// shfl_up scans (2 radix rounds) -> compact <=P16 superset -> register
// bitonic-256 (4 keys/lane, shfl_xor). Key=(sortable_dist<<32)|idx == top_k
// order incl. lower-index ties. keys alias dead position arrays (20.5KB LDS).
// ---------------------------------------------------------------------------
__global__ void k1_kernel(const float* __restrict__ verts, const float* __restrict__ dirs,
                          const float* __restrict__ x,
                          const float* __restrict__ convW, const float* __restrict__ convB,
                          int* __restrict__ idxout, float* __restrict__ sdn,
                          float* __restrict__ st, float* __restrict__ fo)
{
    __shared__ __align__(16) char smem[20544];
    int t = threadIdx.x;
    int blk = blockIdx.x;

    if (blk >= 2048) {
        if (blk == 2054) {                         // dirs normalize: 6x128 cols
            for (int i = t; i < 768; i += 256) {
                int l = i >> 7, k = i & 127;
                float a = dirs[l*384 + k];
                float b = dirs[l*384 + 128 + k];
                float c = dirs[l*384 + 256 + k];
                float nrm = sqrtf(a*a + b*b + c*c);
                float inv = 1.0f / fmaxf(nrm, 1e-12f);
                sdn[l*384 + k]       = a*inv;
                sdn[l*384 + 128 + k] = b*inv;
                sdn[l*384 + 256 + k] = c*inv;
            }
        } else {                                   // zero st: 6 x 256 floats
            st[(blk - 2048)*256 + t] = 0.0f;
        }
        return;
    }
    if (blk >= 512) {                              // gemmA: L0,L1,L3 from x (no BN)
        int g = blk - 512;
        int s = g >> 9, rb = g & 511;
        int wi = (s==0) ? 0 : (s==1) ? 1 : 3;
        gemm_body(x, (const float*)0, (const float*)0, (const float*)0,
                  convW + wi*32768, convB + wi*256, fo + s*524288, rb, smem);
        return;
    }

    // ---------------- knn: one wave per vertex ----------------
    float* xs  = (float*)smem;                     // [0,4K)
    float* ys  = xs + 1024;                        // [4K,8K)
    float* zs  = ys + 1024;                        // [8K,12K)
    float* sqs = zs + 1024;                        // [12K,16K)
    unsigned int* histBase = (unsigned int*)(smem + 16384);   // [16K,20K)
    unsigned int* selBase  = (unsigned int*)(smem + 20480);   // 64 B

    int w = t >> 6;            // wave id 0..3
    int l = t & 63;            // lane
    int vglob = blk*4 + w;
    int b = vglob >> 10;
    int v = vglob & 1023;
    unsigned long long* keys = (unsigned long long*)smem + w*256;  // alias xs/ys (dead)
    unsigned int* hist = histBase + w*256;
    unsigned int* sel  = selBase + w*4;

    const float* vb = verts + b * 3072;
    for (int i = t; i < 1024; i += 256) {
        float xx = vb[i*3+0], yy = vb[i*3+1], zz = vb[i*3+2];
        xs[i] = xx; ys[i] = yy; zs[i] = zz;
        sqs[i] = xx*xx + yy*yy + zz*zz;
    }
    __syncthreads();                               // B1

    float cx = xs[v], cy = ys[v], cz = zs[v], csq = sqs[v];
    unsigned long long K16[16];
    #pragma unroll
    for (int q = 0; q < 16; ++q) {
        int j = q*64 + l;
        float dot = cx*xs[j] + cy*ys[j] + cz*zs[j];
        float d = -2.0f*dot + csq + sqs[j];        // reference formula
        unsigned int u = __float_as_uint(d);
        u = (u & 0x80000000u) ? ~u : (u | 0x80000000u);
        K16[q] = (((unsigned long long)u) << 32) | (unsigned long long)j;
    }
    #pragma unroll
    for (int i = 0; i < 4; ++i) hist[l*4 + i] = 0u;
    __syncthreads();                               // B2 (positions now dead)

    #pragma unroll
    for (int q = 0; q < 16; ++q)
        atomicAdd(&hist[(unsigned int)(K16[q] >> 56)], 1u);
    __syncthreads();                               // B3

    // ---- wave scan round 1: bin & remaining rank of rank-101
    {
        unsigned int h0 = hist[l*4], h1 = hist[l*4+1], h2 = hist[l*4+2], h3 = hist[l*4+3];
        unsigned int c1 = h0, c2 = h0+h1, c3 = h0+h1+h2, T = c3+h3;
        unsigned int xacc = T;
        #pragma unroll
        for (int off = 1; off < 64; off <<= 1) {
            unsigned int y = __shfl_up(xacc, off, 64);
            if (l >= off) xacc += y;
        }
        unsigned int P = xacc - T;
        unsigned int ex[4] = {P, P+c1, P+c2, P+c3};
        unsigned int hh[4] = {h0, h1, h2, h3};
        #pragma unroll
        for (int i = 0; i < 4; ++i) {
            if (ex[i] < 101u && ex[i] + hh[i] >= 101u) {
                sel[0] = (unsigned int)(l*4 + i);
                sel[1] = 101u - ex[i];
            }
        }
    }
    __syncthreads();                               // B4
    unsigned int P8 = sel[0], rank2 = sel[1];
    #pragma unroll
    for (int i = 0; i < 4; ++i) hist[l*4 + i] = 0u;
    __syncthreads();                               // B5

    #pragma unroll
    for (int q = 0; q < 16; ++q)
        if ((unsigned int)(K16[q] >> 56) == P8)
            atomicAdd(&hist[(unsigned int)(K16[q] >> 48) & 0xFFu], 1u);
    __syncthreads();                               // B6

    // ---- wave scan round 2: 16-bit prefix of rank-101 key
    {
        unsigned int h0 = hist[l*4], h1 = hist[l*4+1], h2 = hist[l*4+2], h3 = hist[l*4+3];
        unsigned int c1 = h0, c2 = h0+h1, c3 = h0+h1+h2, T = c3+h3;
        unsigned int xacc = T;
        #pragma unroll
        for (int off = 1; off < 64; off <<= 1) {
            unsigned int y = __shfl_up(xacc, off, 64);
            if (l >= off) xacc += y;
        }
        unsigned int P = xacc - T;
        unsigned int ex[4] = {P, P+c1, P+c2, P+c3};
        unsigned int hh[4] = {h0, h1, h2, h3};
        #pragma unroll
        for (int i = 0; i < 4; ++i) {
            if (ex[i] < rank2 && ex[i] + hh[i] >= rank2) {
                sel[2] = (P8 << 8) | (unsigned int)(l*4 + i);
                sel[3] = 0u;
            }
        }
    }
    __syncthreads();                               // B7
    unsigned int P16 = sel[2];

    // ---- compact superset (>=101 keys, cap 256) into wave-private LDS
    #pragma unroll
    for (int q = 0; q < 16; ++q) {
        if ((unsigned int)(K16[q] >> 48) <= P16) {
            unsigned int pos = atomicAdd(&sel[3], 1u);
            if (pos < 256u) keys[pos] = K16[q];
        }
    }
    __syncthreads();                               // B8
    unsigned int cnt = sel[3];

    // ---- 4 keys/lane, register bitonic-256 (shfl_xor for j>=4)
    unsigned long long K[4];
    #pragma unroll
    for (int q = 0; q < 4; ++q) {
        unsigned int e = (unsigned int)(l*4 + q);
        K[q] = (e < cnt) ? keys[e] : 0xFFFFFFFFFFFFFFFFULL;
    }

    auto cswap = [&](int qa, int qb, int k) {
        int e = (l << 2) + qa;
        bool up = ((e & k) == 0);
        unsigned long long a = K[qa], bb2 = K[qb];
        unsigned long long mn = a < bb2 ? a : bb2;
        unsigned long long mx = a < bb2 ? bb2 : a;
        K[qa] = up ? mn : mx;
        K[qb] = up ? mx : mn;
    };
    #pragma unroll
    for (int k = 2; k <= 256; k <<= 1) {
        for (int j = k >> 1; j >= 4; j >>= 1) {
            int lj = j >> 2;
            #pragma unroll
            for (int q = 0; q < 4; ++q) {
                unsigned long long other = __shfl_xor(K[q], lj, 64);
                int e = (l << 2) + q;
                bool up = ((e & k) == 0);
                bool lower = ((l & lj) == 0);
                bool takeMin = (lower == up);
                unsigned long long mn = K[q] < other ? K[q] : other;
                unsigned long long mx = K[q] < other ? other : K[q];
                K[q] = takeMin ? mn : mx;
            }
        }
        if (k >= 4) { cswap(0, 2, k); cswap(1, 3, k); }
        cswap(0, 1, k); cswap(2, 3, k);
    }

    #pragma unroll
    for (int q = 0; q < 4; ++q) {                  // ranks 1..100 (0 = self)
        int e = l*4 + q;
        if (e >= 1 && e <= 100)
            idxout[vglob*100 + (e-1)] = (int)(K[q] & 0xFFFFFFFFu);
    }
}

// ---------------------------------------------------------------------------
// Agg: prebn[r,k] = fo[r,k] + max_n relu(d_n.sd_k)*fo[nbr,128+k].
// blockIdx.x = row, blockIdx.y = slot. 128 threads = channels. Unroll 5.
// ---------------------------------------------------------------------------
__global__ void agg_kernel(const int* __restrict__ idx, const float* __restrict__ verts,
                           const float* __restrict__ sdn, const float* __restrict__ fo,
                           int n0, int n1, int n2, int d0, int d1, int d2,
                           float* o0, float* o1, float* o2)
{
    __shared__ float4 ds4[100];
    __shared__ int js[100];
    int slot = blockIdx.y;
    int n  = slot==0 ? n0 : slot==1 ? n1 : n2;
    int dI = slot==0 ? d0 : slot==1 ? d1 : d2;
    float* outp = slot==0 ? o0 : slot==1 ? o1 : o2;
    const float* fos = fo + slot * 524288;
    const float* sd = sdn + dI * 384;

    int r = blockIdx.x;
    int b = r >> 10;
    int t = threadIdx.x;
    if (t < n) {
        int j = idx[r*100 + t];
        js[t] = j;
        const float* pj = verts + (b*1024 + j)*3;
        const float* pv = verts + r*3;
        float dx = pj[0]-pv[0], dy = pj[1]-pv[1], dz = pj[2]-pv[2];
        float nm = sqrtf(dx*dx + dy*dy + dz*dz);
        float inv = 1.0f / fmaxf(nm, 1e-12f);
        ds4[t] = make_float4(dx*inv, dy*inv, dz*inv, 0.0f);
    }
    __syncthreads();
    float s0 = sd[t], s1 = sd[128+t], s2 = sd[256+t];
    int bb = b * 1024;
    float m = -3.0e38f;
    for (int q = 0; q < n; q += 5) {
        float th[5];
        const float* p[5];
        #pragma unroll
        for (int u = 0; u < 5; ++u) {
            float4 dq = ds4[q+u];
            th[u] = fmaxf(dq.x*s0 + dq.y*s1 + dq.z*s2, 0.0f);
            p[u] = fos + (size_t)(bb + js[q+u])*256 + 128 + t;
        }
        float vv[5];
        #pragma unroll
        for (int u = 0; u < 5; ++u) vv[u] = *p[u];
        #pragma unroll
        for (int u = 0; u < 5; ++u) m = fmaxf(m, th[u]*vv[u]);
    }
    outp[r*128 + t] = fos[r*256 + t] + m;
}

// ---------------------------------------------------------------------------
// BN stats: per-channel sum/sumsq over 2048 rows. grid (16, nslots).
// ---------------------------------------------------------------------------
__global__ void stats_kernel(const float* p0, const float* p1, const float* p2,
                             int i0, int i1, int i2, float* stats)
{
    int slot = blockIdx.y;
    const float* p = slot==0 ? p0 : slot==1 ? p1 : p2;
    float* st = stats + (slot==0 ? i0 : slot==1 ? i1 : i2) * 256;
    __shared__ float s1[256], s2[256];
    int t = threadIdx.x, k = t & 127, half = t >> 7;
    int r0 = blockIdx.x * 128;
    float sum = 0.0f, sq = 0.0f;
    for (int s = 0; s < 64; ++s) {
        float x = p[(r0 + half + 2*s)*128 + k];
        sum += x; sq += x*x;
    }
    s1[t] = sum; s2[t] = sq;
    __syncthreads();
    if (t < 128) {
        atomicAdd(&st[k],     s1[t] + s1[t+128]);
        atomicAdd(&st[128+k], s2[t] + s2[t+128]);
    }
}

// ---------------------------------------------------------------------------
// Standalone gemm, up to 2 slots via blockIdx.y. grid (512, nslots), 256 thr.
// ---------------------------------------------------------------------------
__global__ void gemm2_kernel(
    const float* inA, const float* stA, const float* gA, const float* beA,
    const float* WA, const float* biA, float* foA,
    const float* inB, const float* stB, const float* gB, const float* beB,
    const float* WB, const float* biB, float* foB)
{
    __shared__ __align__(16) char smem[3072];
    if (blockIdx.y == 0)
        gemm_body(inA, stA, gA, beA, WA, biA, foA, blockIdx.x, smem);
    else
        gemm_body(inB, stB, gB, beB, WB, biB, foB, blockIdx.x, smem);
}

// ---------------------------------------------------------------------------
// Down-proj: row = [bn(p0)|bn(p1)|bn(p2)] (384) -> relu(row @ dW + db).
// 4 rows/block (512 blocks). Thread = 1 row x 4 cols.
// ---------------------------------------------------------------------------
__global__ void down_kernel(
    const float* __restrict__ p0, const float* __restrict__ st0,
    const float* __restrict__ g0, const float* __restrict__ be0,
    const float* __restrict__ p1, const float* __restrict__ st1,
    const float* __restrict__ g1, const float* __restrict__ be1,
    const float* __restrict__ p2, const float* __restrict__ st2,
    const float* __restrict__ g2, const float* __restrict__ be2,
    const float* __restrict__ dW, const float* __restrict__ db,
    float* __restrict__ out)
{
    __shared__ float rows[4*384];
    __shared__ float scale[384], shift[384];
    int t = threadIdx.x;
    int r0 = blockIdx.x * 4;
    for (int c = t; c < 384; c += 256) {
        int seg = c >> 7, cc = c & 127;
        const float* stp = seg==0 ? st0 : seg==1 ? st1 : st2;
        const float* g   = seg==0 ? g0  : seg==1 ? g1  : g2;
        const float* be  = seg==0 ? be0 : seg==1 ? be1 : be2;
        float mu  = stp[cc] * (1.0f/2048.0f);
        float var = stp[128+cc] * (1.0f/2048.0f) - mu*mu;
        float s = rsqrtf(var + 1e-5f) * g[cc];
        scale[c] = s;
        shift[c] = be[cc] - mu*s;
    }
    __syncthreads();
    if (t < 128) {
        int row = t >> 5, c4 = (t & 31) << 2;
        #pragma unroll
        for (int seg = 0; seg < 3; ++seg) {
            const float* ps = seg==0 ? p0 : seg==1 ? p1 : p2;
            float4 v = *(const float4*)(ps + (r0+row)*128 + c4);
            int sc = seg*128 + c4;
            v.x = fmaxf(v.x*scale[sc  ] + shift[sc  ], 0.0f);
            v.y = fmaxf(v.y*scale[sc+1] + shift[sc+1], 0.0f);
            v.z = fmaxf(v.z*scale[sc+2] + shift[sc+2], 0.0f);
            v.w = fmaxf(v.w*scale[sc+3] + shift[sc+3], 0.0f);
            *(float4*)&rows[row*384 + sc] = v;
        }
    }
    __syncthreads();
    int cb = t & 63, row = t >> 6;
    const float* ar = rows + row*384;
    const float4* W4 = (const float4*)dW;
    float4 acc = make_float4(0.f, 0.f, 0.f, 0.f);
    #pragma unroll 4
    for (int k = 0; k < 384; k += 4) {
        float4 a = *(const float4*)(ar + k);
        float4 w;
        w = W4[(k+0)*64+cb]; acc.x += a.x*w.x; acc.y += a.x*w.y; acc.z += a.x*w.z; acc.w += a.x*w.w;
        w = W4[(k+1)*64+cb]; acc.x += a.y*w.x; acc.y += a.y*w.y; acc.z += a.y*w.z; acc.w += a.y*w.w;
        w = W4[(k+2)*64+cb]; acc.x += a.z*w.x; acc.y += a.z*w.y; acc.z += a.z*w.z; acc.w += a.z*w.w;
        w = W4[(k+3)*64+cb]; acc.x += a.w*w.x; acc.y += a.w*w.y; acc.z += a.w*w.z; acc.w += a.w*w.w;
    }
    float4 b4 = ((const float4*)db)[cb];
    float4 o;
    o.x = fmaxf(acc.x + b4.x, 0.0f);
    o.y = fmaxf(acc.y + b4.y, 0.0f);
    o.z = fmaxf(acc.z + b4.z, 0.0f);
    o.w = fmaxf(acc.w + b4.w, 0.0f);
    ((float4*)out)[(r0+row)*64 + cb] = o;
}

// ---------------------------------------------------------------------------
extern "C" void kernel_launch(void* const* d_in, const int* in_sizes, int n_in,
                              void* d_out, int out_size, void* d_ws, size_t ws_size,
                              hipStream_t stream)
{
    (void)in_sizes; (void)n_in; (void)out_size; (void)ws_size;
    const float* verts = (const float*)d_in[0];
    const float* x     = (const float*)d_in[1];
    const float* convW = (const float*)d_in[2];
    const float* convB = (const float*)d_in[3];
    const float* dirs  = (const float*)d_in[4];
    const float* gam   = (const float*)d_in[5];
    const float* bet   = (const float*)d_in[6];
    const float* dW    = (const float*)d_in[7];
    const float* db    = (const float*)d_in[8];
    float* out = (float*)d_out;

    char* ws = (char*)d_ws;
    int*   idxb = (int*)(ws);                    //  819200 B : (2048,100)
    float* sdn  = (float*)(ws + 819200);         //    9216 B : (6,3,128)
    float* st   = (float*)(ws + 828416);         //    6144 B : 6 x 256
    float* fo   = (float*)(ws + 834560);         // 6291456 B : 3 x (2048,256)
    float* p0   = (float*)(ws + 7126016);        // 1 MiB each: (2048,128)
    float* p1   = (float*)(ws + 8174592);
    float* p2   = (float*)(ws + 9223168);
    float* p3   = (float*)(ws + 10271744);
    float* p4   = (float*)(ws + 11320320);
    float* p5   = (float*)(ws + 12368896);       // total ~12.8 MiB

    const float* nf = (const float*)0;
    float* nw = (float*)0;
    float* st0 = st,        *st1 = st + 256,  *st2 = st + 512;
    float* st3 = st + 768,  *st4 = st + 1024, *st5 = st + 1280;

    // K1: wave-sync knn + gemmA (L0,L1,L3 from x; 3x512 blocks) + st zero + dirs
    k1_kernel<<<2055, 256, 0, stream>>>(verts, dirs, x, convW, convB,
                                        idxb, sdn, st, fo);
    // K2: aggA -> p0 (n5,d0), p1 (n20,d1), p3 (n100,d3)
    agg_kernel<<<dim3(2048,3), 128, 0, stream>>>(
        idxb, verts, sdn, fo, 5, 20, 100, 0, 1, 3, p0, p1, p3);
    // K3: statsA
    stats_kernel<<<dim3(16,3), 256, 0, stream>>>(p0, p1, p3, 0, 1, 3, st);
    // K4: gemmB: L2 from bn(p1,st1,g1,b1); L4 from bn(p3,st3,g3,b3)
    gemm2_kernel<<<dim3(512,2), 256, 0, stream>>>(
        p1, st1, gam + 128, bet + 128, convW + 65536,  convB + 512,  fo,
        p3, st3, gam + 384, bet + 384, convW + 131072, convB + 1024, fo + 524288);
    // K5: aggB -> p2 (n20,d2), p4 (n100,d4)
    agg_kernel<<<dim3(2048,2), 128, 0, stream>>>(
        idxb, verts, sdn, fo, 20, 100, 0, 2, 4, 0, p2, p4, nw);
    // K6: statsB
    stats_kernel<<<dim3(16,2), 256, 0, stream>>>(p2, p4, nf, 2, 4, 0, st);
    // K7: gemmC: L5-conv (params3) from bn(p4,st4,g4,b4)
    gemm2_kernel<<<dim3(512,1), 256, 0, stream>>>(
        p4, st4, gam + 512, bet + 512, convW + 98304, convB + 768, fo,
        nf, nf, nf, nf, nf, nf, nw);
    // K8: aggC -> p5 (n100,d3)
    agg_kernel<<<dim3(2048,1), 128, 0, stream>>>(
        idxb, verts, sdn, fo, 100, 0, 0, 3, 0, 0, p5, nw, nw);
    // K9: statsC
    stats_kernel<<<dim3(16,1), 256, 0, stream>>>(p5, nf, nf, 5, 0, 0, st);
    // K10: down: bn(p0,st0,g0,b0) | bn(p2,st2,g2,b2) | bn(p5,st5,g3,b3)
    down_kernel<<<512, 256, 0, stream>>>(
        p0, st0, gam, bet,
        p2, st2, gam + 256, bet + 256,
        p5, st5, gam + 384, bet + 384,
        dW, db, out);
}

// Round 10
// 194.874 us; speedup vs baseline: 1.5245x; 1.1030x over previous
//
#include <hip/hip_runtime.h>

// ---------------------------------------------------------------------------
// GEMM body: out[r0..r0+7, 0..255] = bn_relu?(in rows) @ W(128x256) + bias.
// 8 rows/block, thread = 2 rows x 4 cols. Halves per-wave W traffic vs
// 1 row/thread (L2 W-traffic = 268MB/slot / rows_per_thread).
// Grids stay >= 256 blocks (round-8 lesson: <=128 blocks => starvation).
// st: raw per-channel sum (st[c]) / sumsq (st[128+c]) over 2048 rows.
// ---------------------------------------------------------------------------
__device__ __forceinline__ void gemm_body(
    const float* __restrict__ in, const float* __restrict__ st,
    const float* __restrict__ gm, const float* __restrict__ bt,
    const float* __restrict__ W, const float* __restrict__ bi,
    float* __restrict__ out, int rb, void* smemv)
{
    float* rows  = (float*)smemv;           // 8*128 floats = 4 KB
    float* scale = rows + 1024;             // 128
    float* shift = scale + 128;             // 128
    int t = threadIdx.x;
    if (t < 128) {
        float sc = 1.0f, sf = 0.0f;
        if (st) {
            float mu  = st[t] * (1.0f/2048.0f);
            float var = st[128+t] * (1.0f/2048.0f) - mu*mu;
            sc = rsqrtf(var + 1e-5f) * gm[t];
            sf = bt[t] - mu*sc;
        }
        scale[t] = sc; shift[t] = sf;
    }
    __syncthreads();
    int r0 = rb * 8;
    {                                       // stage 8 rows = 256 float4
        float4 v = ((const float4*)(in + r0*128))[t];
        if (st) {
            int c4 = (t & 31) << 2;
            v.x = fmaxf(v.x*scale[c4  ] + shift[c4  ], 0.0f);
            v.y = fmaxf(v.y*scale[c4+1] + shift[c4+1], 0.0f);
            v.z = fmaxf(v.z*scale[c4+2] + shift[c4+2], 0.0f);
            v.w = fmaxf(v.w*scale[c4+3] + shift[c4+3], 0.0f);
        }
        ((float4*)rows)[t] = v;
    }
    __syncthreads();
    int cb = t & 63, rp = (t >> 6) << 1;    // rows rp, rp+1
    const float* a0r = rows + rp*128;
    const float* a1r = a0r + 128;
    const float4* W4 = (const float4*)W;
    float4 acc0 = make_float4(0.f,0.f,0.f,0.f);
    float4 acc1 = make_float4(0.f,0.f,0.f,0.f);
    #pragma unroll 4
    for (int k = 0; k < 128; k += 4) {
        float4 a0 = *(const float4*)(a0r + k);
        float4 a1 = *(const float4*)(a1r + k);
        float4 w;
        w = W4[(k+0)*64+cb];
        acc0.x += a0.x*w.x; acc0.y += a0.x*w.y; acc0.z += a0.x*w.z; acc0.w += a0.x*w.w;
        acc1.x += a1.x*w.x; acc1.y += a1.x*w.y; acc1.z += a1.x*w.z; acc1.w += a1.x*w.w;
        w = W4[(k+1)*64+cb];
        acc0.x += a0.y*w.x; acc0.y += a0.y*w.y; acc0.z += a0.y*w.z; acc0.w += a0.y*w.w;
        acc1.x += a1.y*w.x; acc1.y += a1.y*w.y; acc1.z += a1.y*w.z; acc1.w += a1.y*w.w;
        w = W4[(k+2)*64+cb];
        acc0.x += a0.z*w.x; acc0.y += a0.z*w.y; acc0.z += a0.z*w.z; acc0.w += a0.z*w.w;
        acc1.x += a1.z*w.x; acc1.y += a1.z*w.y; acc1.z += a1.z*w.z; acc1.w += a1.z*w.w;
        w = W4[(k+3)*64+cb];
        acc0.x += a0.w*w.x; acc0.y += a0.w*w.y; acc0.z += a0.w*w.z; acc0.w += a0.w*w.w;
        acc1.x += a1.w*w.x; acc1.y += a1.w*w.y; acc1.z += a1.w*w.z; acc1.w += a1.w*w.w;
    }
    float4 b4 = ((const float4*)bi)[cb];
    acc0.x += b4.x; acc0.y += b4.y; acc0.z += b4.z; acc0.w += b4.w;
    acc1.x += b4.x; acc1.y += b4.y; acc1.z += b4.z; acc1.w += b4.w;
    ((float4*)out)[(r0+rp  )*64 + cb] = acc0;
    ((float4*)out)[(r0+rp+1)*64 + cb] = acc1;
}

// ---------------------------------------------------------------------------
// K1: wave-sync knn (blocks 0..511, 1 vertex/wave) + gemmA (512..1279:
// 3 slots x 256 blocks of 8 rows) + zero st (1280..1285) + dirs norm (1286).
// knn: 16 dists/lane in regs -> wave-private 256-bin hist -> rank-101 via
// shfl_up scans (2 radix rounds) -> compact <=P16 superset -> register
// bitonic-256 (4 keys/lane, shfl_xor). Key=(sortable_dist<<32)|idx == top_k
// order incl. lower-index ties.
// ---------------------------------------------------------------------------
__global__ void k1_kernel(const float* __restrict__ verts, const float* __restrict__ dirs,
                          const float* __restrict__ x,
                          const float* __restrict__ convW, const float* __restrict__ convB,
                          int* __restrict__ idxout, float* __restrict__ sdn,
                          float* __restrict__ st, float* __restrict__ fo)
{
    __shared__ __align__(16) char smem[20544];
    int t = threadIdx.x;
    int blk = blockIdx.x;

    if (blk >= 1280) {
        if (blk == 1286) {                         // dirs normalize: 6x128 cols
            for (int i = t; i < 768; i += 256) {
                int l = i >> 7, k = i & 127;
                float a = dirs[l*384 + k];
                float b = dirs[l*384 + 128 + k];
                float c = dirs[l*384 + 256 + k];
                float nrm = sqrtf(a*a + b*b + c*c);
                float inv = 1.0f / fmaxf(nrm, 1e-12f);
                sdn[l*384 + k]       = a*inv;
                sdn[l*384 + 128 + k] = b*inv;
                sdn[l*384 + 256 + k] = c*inv;
            }
        } else {                                   // zero st: 6 x 256 floats
            st[(blk - 1280)*256 + t] = 0.0f;
        }
        return;
    }
    if (blk >= 512) {                              // gemmA: L0,L1,L3 from x (no BN)
        int g = blk - 512;
        int s = g >> 8, rb = g & 255;
        int wi = (s==0) ? 0 : (s==1) ? 1 : 3;
        gemm_body(x, (const float*)0, (const float*)0, (const float*)0,
                  convW + wi*32768, convB + wi*256, fo + s*524288, rb, smem);
        return;
    }

    // ---------------- knn: one wave per vertex ----------------
    float* xs  = (float*)smem;                     // [0,4K)
    float* ys  = xs + 1024;                        // [4K,8K)
    float* zs  = ys + 1024;                        // [8K,12K)
    float* sqs = zs + 1024;                        // [12K,16K)
    unsigned int* histBase = (unsigned int*)(smem + 16384);   // [16K,20K)
    unsigned int* selBase  = (unsigned int*)(smem + 20480);   // 64 B

    int w = t >> 6;            // wave id 0..3
    int l = t & 63;            // lane
    int vglob = blk*4 + w;
    int b = vglob >> 10;
    int v = vglob & 1023;
    unsigned long long* keys = (unsigned long long*)smem + w*256;  // alias xs/ys (dead)
    unsigned int* hist = histBase + w*256;
    unsigned int* sel  = selBase + w*4;

    const float* vb = verts + b * 3072;
    for (int i = t; i < 1024; i += 256) {
        float xx = vb[i*3+0], yy = vb[i*3+1], zz = vb[i*3+2];
        xs[i] = xx; ys[i] = yy; zs[i] = zz;
        sqs[i] = xx*xx + yy*yy + zz*zz;
    }
    __syncthreads();                               // B1

    float cx = xs[v], cy = ys[v], cz = zs[v], csq = sqs[v];
    unsigned long long K16[16];
    #pragma unroll
    for (int q = 0; q < 16; ++q) {
        int j = q*64 + l;
        float dot = cx*xs[j] + cy*ys[j] + cz*zs[j];
        float d = -2.0f*dot + csq + sqs[j];        // reference formula
        unsigned int u = __float_as_uint(d);
        u = (u & 0x80000000u) ? ~u : (u | 0x80000000u);
        K16[q] = (((unsigned long long)u) << 32) | (unsigned long long)j;
    }
    #pragma unroll
    for (int i = 0; i < 4; ++i) hist[l*4 + i] = 0u;
    __syncthreads();                               // B2 (positions now dead)

    #pragma unroll
    for (int q = 0; q < 16; ++q)
        atomicAdd(&hist[(unsigned int)(K16[q] >> 56)], 1u);
    __syncthreads();                               // B3

    // ---- wave scan round 1: bin & remaining rank of rank-101
    {
        unsigned int h0 = hist[l*4], h1 = hist[l*4+1], h2 = hist[l*4+2], h3 = hist[l*4+3];
        unsigned int c1 = h0, c2 = h0+h1, c3 = h0+h1+h2, T = c3+h3;
        unsigned int xacc = T;
        #pragma unroll
        for (int off = 1; off < 64; off <<= 1) {
            unsigned int y = __shfl_up(xacc, off, 64);
            if (l >= off) xacc += y;
        }
        unsigned int P = xacc - T;
        unsigned int ex[4] = {P, P+c1, P+c2, P+c3};
        unsigned int hh[4] = {h0, h1, h2, h3};
        #pragma unroll
        for (int i = 0; i < 4; ++i) {
            if (ex[i] < 101u && ex[i] + hh[i] >= 101u) {
                sel[0] = (unsigned int)(l*4 + i);
                sel[1] = 101u - ex[i];
            }
        }
    }
    __syncthreads();                               // B4
    unsigned int P8 = sel[0], rank2 = sel[1];
    #pragma unroll
    for (int i = 0; i < 4; ++i) hist[l*4 + i] = 0u;
    __syncthreads();                               // B5

    #pragma unroll
    for (int q = 0; q < 16; ++q)
        if ((unsigned int)(K16[q] >> 56) == P8)
            atomicAdd(&hist[(unsigned int)(K16[q] >> 48) & 0xFFu], 1u);
    __syncthreads();                               // B6

    // ---- wave scan round 2: 16-bit prefix of rank-101 key
    {
        unsigned int h0 = hist[l*4], h1 = hist[l*4+1], h2 = hist[l*4+2], h3 = hist[l*4+3];
        unsigned int c1 = h0, c2 = h0+h1, c3 = h0+h1+h2, T = c3+h3;
        unsigned int xacc = T;
        #pragma unroll
        for (int off = 1; off < 64; off <<= 1) {
            unsigned int y = __shfl_up(xacc, off, 64);
            if (l >= off) xacc += y;
        }
        unsigned int P = xacc - T;
        unsigned int ex[4] = {P, P+c1, P+c2, P+c3};
        unsigned int hh[4] = {h0, h1, h2, h3};
        #pragma unroll
        for (int i = 0; i < 4; ++i) {
            if (ex[i] < rank2 && ex[i] + hh[i] >= rank2) {
                sel[2] = (P8 << 8) | (unsigned int)(l*4 + i);
                sel[3] = 0u;
            }
        }
    }
    __syncthreads();                               // B7
    unsigned int P16 = sel[2];

    // ---- compact superset (>=101 keys, cap 256) into wave-private LDS
    #pragma unroll
    for (int q = 0; q < 16; ++q) {
        if ((unsigned int)(K16[q] >> 48) <= P16) {
            unsigned int pos = atomicAdd(&sel[3], 1u);
            if (pos < 256u) keys[pos] = K16[q];
        }
    }
    __syncthreads();                               // B8
    unsigned int cnt = sel[3];

    // ---- 4 keys/lane, register bitonic-256 (shfl_xor for j>=4)
    unsigned long long K[4];
    #pragma unroll
    for (int q = 0; q < 4; ++q) {
        unsigned int e = (unsigned int)(l*4 + q);
        K[q] = (e < cnt) ? keys[e] : 0xFFFFFFFFFFFFFFFFULL;
    }

    auto cswap = [&](int qa, int qb, int k) {
        int e = (l << 2) + qa;
        bool up = ((e & k) == 0);
        unsigned long long a = K[qa], bb2 = K[qb];
        unsigned long long mn = a < bb2 ? a : bb2;
        unsigned long long mx = a < bb2 ? bb2 : a;
        K[qa] = up ? mn : mx;
        K[qb] = up ? mx : mn;
    };
    #pragma unroll
    for (int k = 2; k <= 256; k <<= 1) {
        for (int j = k >> 1; j >= 4; j >>= 1) {
            int lj = j >> 2;
            #pragma unroll
            for (int q = 0; q < 4; ++q) {
                unsigned long long other = __shfl_xor(K[q], lj, 64);
                int e = (l << 2) + q;
                bool up = ((e & k) == 0);
                bool lower = ((l & lj) == 0);
                bool takeMin = (lower == up);
                unsigned long long mn = K[q] < other ? K[q] : other;
                unsigned long long mx = K[q] < other ? other : K[q];
                K[q] = takeMin ? mn : mx;
            }
        }
        if (k >= 4) { cswap(0, 2, k); cswap(1, 3, k); }
        cswap(0, 1, k); cswap(2, 3, k);
    }

    #pragma unroll
    for (int q = 0; q < 4; ++q) {                  // ranks 1..100 (0 = self)
        int e = l*4 + q;
        if (e >= 1 && e <= 100)
            idxout[vglob*100 + (e-1)] = (int)(K[q] & 0xFFFFFFFFu);
    }
}

// ---------------------------------------------------------------------------
// Agg: prebn[r,k] = fo[r,k] + max_n relu(d_n.sd_k)*fo[nbr,128+k].
// blockIdx.x = row, blockIdx.y = slot. 128 threads = channels. Unroll 5.
// ---------------------------------------------------------------------------
__global__ void agg_kernel(const int* __restrict__ idx, const float* __restrict__ verts,
                           const float* __restrict__ sdn, const float* __restrict__ fo,
                           int n0, int n1, int n2, int d0, int d1, int d2,
                           float* o0, float* o1, float* o2)
{
    __shared__ float4 ds4[100];
    __shared__ int js[100];
    int slot = blockIdx.y;
    int n  = slot==0 ? n0 : slot==1 ? n1 : n2;
    int dI = slot==0 ? d0 : slot==1 ? d1 : d2;
    float* outp = slot==0 ? o0 : slot==1 ? o1 : o2;
    const float* fos = fo + slot * 524288;
    const float* sd = sdn + dI * 384;

    int r = blockIdx.x;
    int b = r >> 10;
    int t = threadIdx.x;
    if (t < n) {
        int j = idx[r*100 + t];
        js[t] = j;
        const float* pj = verts + (b*1024 + j)*3;
        const float* pv = verts + r*3;
        float dx = pj[0]-pv[0], dy = pj[1]-pv[1], dz = pj[2]-pv[2];
        float nm = sqrtf(dx*dx + dy*dy + dz*dz);
        float inv = 1.0f / fmaxf(nm, 1e-12f);
        ds4[t] = make_float4(dx*inv, dy*inv, dz*inv, 0.0f);
    }
    __syncthreads();
    float s0 = sd[t], s1 = sd[128+t], s2 = sd[256+t];
    int bb = b * 1024;
    float m = -3.0e38f;
    for (int q = 0; q < n; q += 5) {
        float th[5];
        const float* p[5];
        #pragma unroll
        for (int u = 0; u < 5; ++u) {
            float4 dq = ds4[q+u];
            th[u] = fmaxf(dq.x*s0 + dq.y*s1 + dq.z*s2, 0.0f);
            p[u] = fos + (size_t)(bb + js[q+u])*256 + 128 + t;
        }
        float vv[5];
        #pragma unroll
        for (int u = 0; u < 5; ++u) vv[u] = *p[u];
        #pragma unroll
        for (int u = 0; u < 5; ++u) m = fmaxf(m, th[u]*vv[u]);
    }
    outp[r*128 + t] = fos[r*256 + t] + m;
}

// ---------------------------------------------------------------------------
// BN stats: per-channel sum/sumsq over 2048 rows. grid (16, nslots).
// ---------------------------------------------------------------------------
__global__ void stats_kernel(const float* p0, const float* p1, const float* p2,
                             int i0, int i1, int i2, float* stats)
{
    int slot = blockIdx.y;
    const float* p = slot==0 ? p0 : slot==1 ? p1 : p2;
    float* st = stats + (slot==0 ? i0 : slot==1 ? i1 : i2) * 256;
    __shared__ float s1[256], s2[256];
    int t = threadIdx.x, k = t & 127, half = t >> 7;
    int r0 = blockIdx.x * 128;
    float sum = 0.0f, sq = 0.0f;
    for (int s = 0; s < 64; ++s) {
        float x = p[(r0 + half + 2*s)*128 + k];
        sum += x; sq += x*x;
    }
    s1[t] = sum; s2[t] = sq;
    __syncthreads();
    if (t < 128) {
        atomicAdd(&st[k],     s1[t] + s1[t+128]);
        atomicAdd(&st[128+k], s2[t] + s2[t+128]);
    }
}

// ---------------------------------------------------------------------------
// Standalone gemm, up to 2 slots via blockIdx.y. grid (256, nslots), 256 thr.
// ---------------------------------------------------------------------------
__global__ void gemm2_kernel(
    const float* inA, const float* stA, const float* gA, const float* beA,
    const float* WA, const float* biA, float* foA,
    const float* inB, const float* stB, const float* gB, const float* beB,
    const float* WB, const float* biB, float* foB)
{
    __shared__ __align__(16) char smem[5120];
    if (blockIdx.y == 0)
        gemm_body(inA, stA, gA, beA, WA, biA, foA, blockIdx.x, smem);
    else
        gemm_body(inB, stB, gB, beB, WB, biB, foB, blockIdx.x, smem);
}

// ---------------------------------------------------------------------------
// Down-proj: row = [bn(p0)|bn(p1)|bn(p2)] (384) -> relu(row @ dW + db).
// 8 rows/block (256 blocks). Thread = 2 rows x 4 cols.
// ---------------------------------------------------------------------------
__global__ void down_kernel(
    const float* __restrict__ p0, const float* __restrict__ st0,
    const float* __restrict__ g0, const float* __restrict__ be0,
    const float* __restrict__ p1, const float* __restrict__ st1,
    const float* __restrict__ g1, const float* __restrict__ be1,
    const float* __restrict__ p2, const float* __restrict__ st2,
    const float* __restrict__ g2, const float* __restrict__ be2,
    const float* __restrict__ dW, const float* __restrict__ db,
    float* __restrict__ out)
{
    __shared__ float rows[8*384];          // 12 KB
    __shared__ float scale[384], shift[384];
    int t = threadIdx.x;
    int r0 = blockIdx.x * 8;
    for (int c = t; c < 384; c += 256) {
        int seg = c >> 7, cc = c & 127;
        const float* stp = seg==0 ? st0 : seg==1 ? st1 : st2;
        const float* g   = seg==0 ? g0  : seg==1 ? g1  : g2;
        const float* be  = seg==0 ? be0 : seg==1 ? be1 : be2;
        float mu  = stp[cc] * (1.0f/2048.0f);
        float var = stp[128+cc] * (1.0f/2048.0f) - mu*mu;
        float s = rsqrtf(var + 1e-5f) * g[cc];
        scale[c] = s;
        shift[c] = be[cc] - mu*s;
    }
    __syncthreads();
    for (int q = t; q < 768; q += 256) {   // 8 rows x 96 float4
        int row = q / 96, rem = q - row*96;
        int c4 = rem << 2;                 // 0..380 within 384-concat
        int seg = c4 >> 7, cc = c4 & 127;
        const float* ps = seg==0 ? p0 : seg==1 ? p1 : p2;
        float4 v = *(const float4*)(ps + (r0+row)*128 + cc);
        v.x = fmaxf(v.x*scale[c4  ] + shift[c4  ], 0.0f);
        v.y = fmaxf(v.y*scale[c4+1] + shift[c4+1], 0.0f);
        v.z = fmaxf(v.z*scale[c4+2] + shift[c4+2], 0.0f);
        v.w = fmaxf(v.w*scale[c4+3] + shift[c4+3], 0.0f);
        *(float4*)&rows[row*384 + c4] = v;
    }
    __syncthreads();
    int cb = t & 63, rp = (t >> 6) << 1;
    const float* a0r = rows + rp*384;
    const float* a1r = a0r + 384;
    const float4* W4 = (const float4*)dW;
    float4 acc0 = make_float4(0.f,0.f,0.f,0.f);
    float4 acc1 = make_float4(0.f,0.f,0.f,0.f);
    #pragma unroll 4
    for (int k = 0; k < 384; k += 4) {
        float4 a0 = *(const float4*)(a0r + k);
        float4 a1 = *(const float4*)(a1r + k);
        float4 w;
        w = W4[(k+0)*64+cb];
        acc0.x += a0.x*w.x; acc0.y += a0.x*w.y; acc0.z += a0.x*w.z; acc0.w += a0.x*w.w;
        acc1.x += a1.x*w.x; acc1.y += a1.x*w.y; acc1.z += a1.x*w.z; acc1.w += a1.x*w.w;
        w = W4[(k+1)*64+cb];
        acc0.x += a0.y*w.x; acc0.y += a0.y*w.y; acc0.z += a0.y*w.z; acc0.w += a0.y*w.w;
        acc1.x += a1.y*w.x; acc1.y += a1.y*w.y; acc1.z += a1.y*w.z; acc1.w += a1.y*w.w;
        w = W4[(k+2)*64+cb];
        acc0.x += a0.z*w.x; acc0.y += a0.z*w.y; acc0.z += a0.z*w.z; acc0.w += a0.z*w.w;
        acc1.x += a1.z*w.x; acc1.y += a1.z*w.y; acc1.z += a1.z*w.z; acc1.w += a1.z*w.w;
        w = W4[(k+3)*64+cb];
        acc0.x += a0.w*w.x; acc0.y += a0.w*w.y; acc0.z += a0.w*w.z; acc0.w += a0.w*w.w;
        acc1.x += a1.w*w.x; acc1.y += a1.w*w.y; acc1.z += a1.w*w.z; acc1.w += a1.w*w.w;
    }
    float4 b4 = ((const float4*)db)[cb];
    float4 o0, o1;
    o0.x = fmaxf(acc0.x + b4.x, 0.0f); o0.y = fmaxf(acc0.y + b4.y, 0.0f);
    o0.z = fmaxf(acc0.z + b4.z, 0.0f); o0.w = fmaxf(acc0.w + b4.w, 0.0f);
    o1.x = fmaxf(acc1.x + b4.x, 0.0f); o1.y = fmaxf(acc1.y + b4.y, 0.0f);
    o1.z = fmaxf(acc1.z + b4.z, 0.0f); o1.w = fmaxf(acc1.w + b4.w, 0.0f);
    ((float4*)out)[(r0+rp  )*64 + cb] = o0;
    ((float4*)out)[(r0+rp+1)*64 + cb] = o1;
}

// ---------------------------------------------------------------------------
extern "C" void kernel_launch(void* const* d_in, const int* in_sizes, int n_in,
                              void* d_out, int out_size, void* d_ws, size_t ws_size,
                              hipStream_t stream)
{
    (void)in_sizes; (void)n_in; (void)out_size; (void)ws_size;
    const float* verts = (const float*)d_in[0];
    const float* x     = (const float*)d_in[1];
    const float* convW = (const float*)d_in[2];
    const float* convB = (const float*)d_in[3];
    const float* dirs  = (const float*)d_in[4];
    const float* gam   = (const float*)d_in[5];
    const float* bet   = (const float*)d_in[6];
    const float* dW    = (const float*)d_in[7];
    const float* db    = (const float*)d_in[8];
    float* out = (float*)d_out;

    char* ws = (char*)d_ws;
    int*   idxb = (int*)(ws);                    //  819200 B : (2048,100)
    float* sdn  = (float*)(ws + 819200);         //    9216 B : (6,3,128)
    float* st   = (float*)(ws + 828416);         //    6144 B : 6 x 256
    float* fo   = (float*)(ws + 834560);         // 6291456 B : 3 x (2048,256)
    float* p0   = (float*)(ws + 7126016);        // 1 MiB each: (2048,128)
    float* p1   = (float*)(ws + 8174592);
    float* p2   = (float*)(ws + 9223168);
    float* p3   = (float*)(ws + 10271744);
    float* p4   = (float*)(ws + 11320320);
    float* p5   = (float*)(ws + 12368896);       // total ~12.8 MiB

    const float* nf = (const float*)0;
    float* nw = (float*)0;
    float* st0 = st,        *st1 = st + 256,  *st2 = st + 512;
    float* st3 = st + 768,  *st4 = st + 1024, *st5 = st + 1280;

    // K1: wave-sync knn + gemmA (L0,L1,L3 from x; 3x256 blocks) + st zero + dirs
    k1_kernel<<<1287, 256, 0, stream>>>(verts, dirs, x, convW, convB,
                                        idxb, sdn, st, fo);
    // K2: aggA -> p0 (n5,d0), p1 (n20,d1), p3 (n100,d3)
    agg_kernel<<<dim3(2048,3), 128, 0, stream>>>(
        idxb, verts, sdn, fo, 5, 20, 100, 0, 1, 3, p0, p1, p3);
    // K3: statsA
    stats_kernel<<<dim3(16,3), 256, 0, stream>>>(p0, p1, p3, 0, 1, 3, st);
    // K4: gemmB: L2 from bn(p1,st1,g1,b1); L4 from bn(p3,st3,g3,b3)
    gemm2_kernel<<<dim3(256,2), 256, 0, stream>>>(
        p1, st1, gam + 128, bet + 128, convW + 65536,  convB + 512,  fo,
        p3, st3, gam + 384, bet + 384, convW + 131072, convB + 1024, fo + 524288);
    // K5: aggB -> p2 (n20,d2), p4 (n100,d4)
    agg_kernel<<<dim3(2048,2), 128, 0, stream>>>(
        idxb, verts, sdn, fo, 20, 100, 0, 2, 4, 0, p2, p4, nw);
    // K6: statsB
    stats_kernel<<<dim3(16,2), 256, 0, stream>>>(p2, p4, nf, 2, 4, 0, st);
    // K7: gemmC: L5-conv (params3) from bn(p4,st4,g4,b4)
    gemm2_kernel<<<dim3(256,1), 256, 0, stream>>>(
        p4, st4, gam + 512, bet + 512, convW + 98304, convB + 768, fo,
        nf, nf, nf, nf, nf, nf, nw);
    // K8: aggC -> p5 (n100,d3)
    agg_kernel<<<dim3(2048,1), 128, 0, stream>>>(
        idxb, verts, sdn, fo, 100, 0, 0, 3, 0, 0, p5, nw, nw);
    // K9: statsC
    stats_kernel<<<dim3(16,1), 256, 0, stream>>>(p5, nf, nf, 5, 0, 0, st);
    // K10: down: bn(p0,st0,g0,b0) | bn(p2,st2,g2,b2) | bn(p5,st5,g3,b3)
    down_kernel<<<256, 256, 0, stream>>>(
        p0, st0, gam, bet,
        p2, st2, gam + 256, bet + 256,
        p5, st5, gam + 384, bet + 384,
        dW, db, out);
}